// Round 3
// baseline (961.463 us; speedup 1.0000x reference)
//
#include <hip/hip_runtime.h>
#include <math.h>

#define BS   8
#define TT   1024
#define DD   512
#define HH   8
#define LL   4
#define FFD  2048
#define NCC  10
#define MM   (BS*TT)
#define MDl  ((long)MM*DD)

typedef unsigned short u16;
typedef short  short8 __attribute__((ext_vector_type(8)));
typedef float  f32x4  __attribute__((ext_vector_type(4)));
typedef u16    u16x8  __attribute__((ext_vector_type(8)));
typedef u16    u16x4  __attribute__((ext_vector_type(4)));

static __device__ __forceinline__ u16 f2b(float f) {
    union { float f; unsigned u; } x; x.f = f;
    unsigned r = x.u + 0x7FFFu + ((x.u >> 16) & 1u);   // RNE
    return (u16)(r >> 16);
}
// round-half-up: 2 insts, differs from RNE only on exact ties (negligible)
static __device__ __forceinline__ u16 f2b_fast(float f) {
    union { float f; unsigned u; } x; x.f = f;
    return (u16)((x.u + 0x8000u) >> 16);
}
static __device__ __forceinline__ float b2f(u16 u) {
    union { unsigned u; float f; } x; x.u = ((unsigned)u) << 16;
    return x.f;
}

// ---------------------------------------------------------------------------
// Embedding + sinusoidal positional encoding  (X fp32)
// ---------------------------------------------------------------------------
__global__ __launch_bounds__(256)
void embed_kernel(const int* __restrict__ tok, const float* __restrict__ emb,
                  float* __restrict__ X) {
    int i = blockIdx.x * 256 + threadIdx.x;
    int d = i & (DD - 1);
    int row = i >> 9;
    int t = row & (TT - 1);
    int j = d >> 1;
    float freq = __expf((float)(2 * j) * (-9.210340371976184f / 512.0f));
    float ang = (float)t * freq;
    float pe = (d & 1) ? cosf(ang) : sinf(ang);
    X[i] = emb[(long)tok[row] * DD + d] + pe;
}

// ---------------------------------------------------------------------------
// LayerNorm over D=512; OUTBF: 1 -> bf16 out, 0 -> fp32 out
// ---------------------------------------------------------------------------
template<int OUTBF>
__global__ __launch_bounds__(256)
void ln_kernel(const float* __restrict__ in, void* __restrict__ outp,
               const float* __restrict__ g, const float* __restrict__ b) {
    int row = blockIdx.x;
    int tid = threadIdx.x;
    const float* x = in + (long)row * DD;
    float x1 = x[tid], x2 = x[tid + 256];
    __shared__ float red[256], red2[256];
    red[tid] = x1 + x2;
    red2[tid] = x1 * x1 + x2 * x2;
    __syncthreads();
    for (int st = 128; st > 0; st >>= 1) {
        if (tid < st) { red[tid] += red[tid + st]; red2[tid] += red2[tid + st]; }
        __syncthreads();
    }
    float mean = red[0] * (1.0f / DD);
    float var = red2[0] * (1.0f / DD) - mean * mean;
    float rstd = rsqrtf(var + 1e-5f);
    float y1 = (x1 - mean) * rstd * g[tid] + b[tid];
    float y2 = (x2 - mean) * rstd * g[tid + 256] + b[tid + 256];
    if (OUTBF) {
        u16* o = (u16*)outp + (long)row * DD;
        o[tid] = f2b(y1); o[tid + 256] = f2b(y2);
    } else {
        float* o = (float*)outp + (long)row * DD;
        o[tid] = y1; o[tid + 256] = y2;
    }
}

// ---------------------------------------------------------------------------
// bf16 MFMA GEMM: C[M=8192, N] = epi(A[M,K] @ W), W given as WT[N][K] bf16.
// 128x128 tile, BK=64, 512 threads (8 waves). Register-prefetch pipeline.
// ---------------------------------------------------------------------------
template<int OUTBF, int HAS_BIAS, int ACT, int HAS_RES>
__global__ __launch_bounds__(512, 2)
void mfma_gemm(const u16* __restrict__ A, const u16* __restrict__ BT,
               const float* __restrict__ bias, const float* __restrict__ R,
               void* __restrict__ Cout, int N, int K) {
    __shared__ __align__(16) u16 lds[17408];   // As(8192)+Bs(8192) | Cs(128x136)
    u16* As = lds;
    u16* Bs = lds + 8192;
    const int tid = threadIdx.x;
    const int lane = tid & 63;
    const int w = tid >> 6;                    // 0..7
    const int wm = w >> 1;                     // 0..3: rows [wm*32, wm*32+32)
    const int wn = w & 1;                      // 0..1: cols [wn*64, wn*64+64)
    const long bm = (long)blockIdx.y * 128;
    const long bn = (long)blockIdx.x * 128;

    f32x4 acc[2][4];
#pragma unroll
    for (int i = 0; i < 2; ++i)
#pragma unroll
        for (int j = 0; j < 4; ++j) acc[i][j] = {0.f, 0.f, 0.f, 0.f};

    // staging: thread -> row tid>>2 (0..127), chunks (tid&3)*2 + {0,1}
    const int srow = tid >> 2;
    const int sc0 = (tid & 3) * 2;
    const u16* Ag = A + (bm + srow) * K + sc0 * 8;
    const u16* Bg = BT + (bn + srow) * K + sc0 * 8;
    int soff[2];
#pragma unroll
    for (int j = 0; j < 2; ++j)
        soff[j] = srow * 64 + ((sc0 + j) ^ (srow & 7)) * 8;

    const int fr = lane & 15;
    const int g = lane >> 4;
    const int am0 = wm * 32 + fr;
    const int bn0 = wn * 64 + fr;
    const int sw = fr & 7;

    u16x8 sa[2][2], sb[2][2];
#pragma unroll
    for (int j = 0; j < 2; ++j) {          // prologue: tile k0=0 -> regs
        sa[0][j] = *(const u16x8*)(Ag + j * 8);
        sb[0][j] = *(const u16x8*)(Bg + j * 8);
    }

    for (int k0 = 0; k0 < K; k0 += 128) {
#pragma unroll
        for (int half = 0; half < 2; ++half) {
            const int cb = half, nb = half ^ 1;
            __syncthreads();               // prior frag reads done
#pragma unroll
            for (int j = 0; j < 2; ++j) {
                *(u16x8*)&As[soff[j]] = sa[cb][j];
                *(u16x8*)&Bs[soff[j]] = sb[cb][j];
            }
            const int knext = k0 + (half + 1) * 64;
            if (knext < K) {               // prefetch next tile -> regs
#pragma unroll
                for (int j = 0; j < 2; ++j) {
                    sa[nb][j] = *(const u16x8*)(Ag + knext + j * 8);
                    sb[nb][j] = *(const u16x8*)(Bg + knext + j * 8);
                }
            }
            __syncthreads();               // staged tile visible
#pragma unroll
            for (int kk = 0; kk < 2; ++kk) {
                const int pos = ((kk << 2) + g) ^ sw;
                short8 af[2], bfv[4];
#pragma unroll
                for (int mi = 0; mi < 2; ++mi)
                    af[mi] = *(const short8*)&As[(am0 + mi * 16) * 64 + pos * 8];
#pragma unroll
                for (int ni = 0; ni < 4; ++ni)
                    bfv[ni] = *(const short8*)&Bs[(bn0 + ni * 16) * 64 + pos * 8];
#pragma unroll
                for (int mi = 0; mi < 2; ++mi)
#pragma unroll
                    for (int ni = 0; ni < 4; ++ni)
                        acc[mi][ni] = __builtin_amdgcn_mfma_f32_16x16x32_bf16(
                            af[mi], bfv[ni], acc[mi][ni], 0, 0, 0);
            }
        }
    }

    // C/D layout: col = lane&15, row = (lane>>4)*4 + reg
    const int erow0 = wm * 32 + g * 4;
    const int ecol0 = wn * 64 + fr;

    if (OUTBF) {
        __syncthreads();
#pragma unroll
        for (int ni = 0; ni < 4; ++ni) {
            const long col = bn + ecol0 + ni * 16;
            float bv = 0.f;
            if (HAS_BIAS) bv = bias[col];
#pragma unroll
            for (int mi = 0; mi < 2; ++mi)
#pragma unroll
                for (int r = 0; r < 4; ++r) {
                    const int row = erow0 + mi * 16 + r;
                    float v = acc[mi][ni][r];
                    if (HAS_BIAS) v += bv;
                    if (ACT == 1) v = 0.5f * v * (1.0f + erff(v * 0.70710678118654752f));
                    if (ACT == 2) v = tanhf(v);
                    if (HAS_RES) v += R[(bm + row) * N + col];
                    lds[row * 136 + ecol0 + ni * 16] = f2b(v);
                }
        }
        __syncthreads();
        const int srow2 = tid >> 4;                // 0..31
        const int sch2 = tid & 15;
        u16* Cp = (u16*)Cout;
#pragma unroll
        for (int rr = 0; rr < 4; ++rr) {
            const int row = srow2 + rr * 32;
            u16x8 vv = *(const u16x8*)&lds[row * 136 + sch2 * 8];
            *(u16x8*)(Cp + (bm + row) * N + bn + sch2 * 8) = vv;
        }
    } else {
#pragma unroll
        for (int ni = 0; ni < 4; ++ni) {
            const long col = bn + ecol0 + ni * 16;
            float bv = 0.f;
            if (HAS_BIAS) bv = bias[col];
#pragma unroll
            for (int mi = 0; mi < 2; ++mi)
#pragma unroll
                for (int r = 0; r < 4; ++r) {
                    const long row = bm + erow0 + mi * 16 + r;
                    float v = acc[mi][ni][r];
                    if (HAS_BIAS) v += bv;
                    if (ACT == 1) v = 0.5f * v * (1.0f + erff(v * 0.70710678118654752f));
                    if (ACT == 2) v = tanhf(v);
                    if (HAS_RES) v += R[row * N + col];
                    ((float*)Cout)[row * N + col] = v;
                }
        }
    }
}

// ---------------------------------------------------------------------------
// MFMA flash attention — R9: barrier-free swapped-QK (R8 structure, precision
// fix). R8 failed absmax 6.8e-3 vs 4.55e-3: the inline-asm v_cvt_pk_bf16_f32
// was the only unverified numerical element (rounding mode / operand order
// both suspect; guide m240 says don't hand-write it). Fix: pack P with the
// R7-proven f2b_fast + shifts, and sum the bf16-ROUNDED P values into lsum so
// numerator and denominator are exactly consistent.
// Structure (unchanged from R8):
//  * swapped QK^T: mfma(K,Q) -> lane holds P[q=lane&15][keys g*4+r] == the PV
//    A-frag layout (k-slot g*8+j -> key g*4+j for j<4, zeros j>=4; V B-frag
//    uses the same k-slot map so zeros cancel). P never touches LDS.
//  * waves own KEY slices; K-frags direct from global (L2-resident); only the
//    private 16-key V^T slice goes through LDS -> NO barriers in main loop.
//  * cross-wave O/lsum reduction once at block end.
// Block: 64 q, 4 waves, grid 1024 with XCD swizzle (FETCH 12MB proven in R7).
// ---------------------------------------------------------------------------
__global__ __launch_bounds__(256, 2)
void attn_kernel(const u16* __restrict__ QKV, u16* __restrict__ O) {
    const int id = blockIdx.x;                 // 0..1023
    const int bh = ((id >> 7) << 3) | (id & 7);// bhHi*8 + xcd, 0..63
    const int qblk = (id >> 3) & 15;           // 0..15
    const int h = bh & 7;
    const int b = bh >> 3;
    const int tid = threadIdx.x;
    const int lane = tid & 63;
    const int w = tid >> 6;                    // 0..3 : keys [w*16, w*16+16)
    const int fr = lane & 15;
    const int g = lane >> 4;

    __shared__ __align__(16) unsigned char smem[20480];
    u16* Vt = (u16*)smem;                      // [w][buf][64*20] u16
    float (*Ored)[16][68] = (float(*)[16][68])smem;  // [4][16][68] f32
    __shared__ float Lred[4][4][16];

    const long rowb = (long)b * TT;
    const int q0 = qblk * 64;

    // Q fragments (held all kernel): qf[qt][hf], q = q0+qt*16+fr, d = hf*32+g*8
    short8 qf[4][2];
#pragma unroll
    for (int qt = 0; qt < 4; ++qt)
#pragma unroll
        for (int hf = 0; hf < 2; ++hf)
            qf[qt][hf] = *(const short8*)(QKV + (rowb + q0 + qt * 16 + fr) * 1536
                                          + h * 64 + hf * 32 + g * 8);

    f32x4 accO[4][4];
    float lsum[4];
#pragma unroll
    for (int qt = 0; qt < 4; ++qt) {
        lsum[qt] = 0.f;
#pragma unroll
        for (int nt = 0; nt < 4; ++nt) accO[qt][nt] = {0.f, 0.f, 0.f, 0.f};
    }

    const int vkp = lane & 7;                  // key pair 2vkp, 2vkp+1
    const int vd0 = (lane >> 3) * 8;           // 8 d values
    u16* Vw0 = Vt + w * 2560;                  // wave's 2 buffers (u16 units)

    auto load_k = [&](int kt_, u16x8* kr_) {
        const u16* kp = QKV + (rowb + (long)kt_ * 64 + w * 16 + fr) * 1536
                        + 512 + h * 64 + g * 8;
        kr_[0] = *(const u16x8*)kp;
        kr_[1] = *(const u16x8*)(kp + 32);
    };
    auto load_v = [&](int kt_, u16x8* vr_) {
        const u16* vp = QKV + (rowb + (long)kt_ * 64 + w * 16 + vkp * 2) * 1536
                        + 1024 + h * 64 + vd0;
        vr_[0] = *(const u16x8*)vp;
        vr_[1] = *(const u16x8*)(vp + 1536);
    };
    auto stage_v = [&](int buf, u16x8* vr_) {
        unsigned* Vt32 = (unsigned*)(Vw0 + buf * 1280);
#pragma unroll
        for (int j = 0; j < 8; ++j)
            Vt32[(vd0 + j) * 10 + vkp] =
                (unsigned)vr_[0][j] | ((unsigned)vr_[1][j] << 16);
    };
    auto compute = [&](int buf, u16x8* kr_) {
        const u16* Vw = Vw0 + buf * 1280;
        // V B-frags (shared over qt): elem j<4 = V[key g*4+j][d=nt*16+fr], j>=4 = 0
        short8 vb[4];
#pragma unroll
        for (int nt = 0; nt < 4; ++nt) {
            union { short8 s; u16x4 h2[2]; } u;
            u.h2[0] = *(const u16x4*)(Vw + (nt * 16 + fr) * 20 + g * 4);
            u.h2[1] = (u16x4){0, 0, 0, 0};
            vb[nt] = u.s;
        }
#pragma unroll
        for (int qt = 0; qt < 4; ++qt) {
            f32x4 st = {0.f, 0.f, 0.f, 0.f};
            st = __builtin_amdgcn_mfma_f32_16x16x32_bf16(kr_[0], qf[qt][0], st, 0, 0, 0);
            st = __builtin_amdgcn_mfma_f32_16x16x32_bf16(kr_[1], qf[qt][1], st, 0, 0, 0);
            // P -> bf16 via proven f2b_fast; lsum sums the ROUNDED values so
            // softmax numerator/denominator are exactly consistent.
            u16 p0 = f2b_fast(exp2f(st[0] * 0.18033688011112042f));
            u16 p1 = f2b_fast(exp2f(st[1] * 0.18033688011112042f));
            u16 p2 = f2b_fast(exp2f(st[2] * 0.18033688011112042f));
            u16 p3 = f2b_fast(exp2f(st[3] * 0.18033688011112042f));
            lsum[qt] += (b2f(p0) + b2f(p1)) + (b2f(p2) + b2f(p3));
            union { short8 s; unsigned u[4]; } pu;
            pu.u[0] = (unsigned)p0 | ((unsigned)p1 << 16);
            pu.u[1] = (unsigned)p2 | ((unsigned)p3 << 16);
            pu.u[2] = 0; pu.u[3] = 0;
#pragma unroll
            for (int nt = 0; nt < 4; ++nt)
                accO[qt][nt] = __builtin_amdgcn_mfma_f32_16x16x32_bf16(
                    pu.s, vb[nt], accO[qt][nt], 0, 0, 0);
        }
    };

    u16x8 krA[2], vrA[2], krB[2], vrB[2];
    load_k(0, krA); load_v(0, vrA);
    load_k(1, krB); load_v(1, vrB);
    stage_v(0, vrA);

#pragma unroll 1
    for (int kt = 0; kt < 16; kt += 2) {
        stage_v(1, vrB);                          // tile kt+1 (loaded >=1 tile ago)
        compute(0, krA);                          // tile kt
        if (kt + 2 < 16) { load_k(kt + 2, krA); load_v(kt + 2, vrA); }
        compute(1, krB);                          // tile kt+1
        if (kt + 2 < 16) {
            stage_v(0, vrA);                      // tile kt+2 (arrived during compute)
            load_k(kt + 3, krB); load_v(kt + 3, vrB);
        }
    }

    // lsum: reduce over g-groups (keys g*4+r live per-g), publish per wave
#pragma unroll
    for (int qt = 0; qt < 4; ++qt) {
        float s = lsum[qt];
        s += __shfl_xor(s, 16, 64);
        s += __shfl_xor(s, 32, 64);
        Lred[w][qt][fr] = s;                      // 4 lanes same addr+value, benign
    }
    __syncthreads();                              // all waves done with Vt + Lred

    const int q_ = tid >> 4;                      // 0..15
    const int d0 = (tid & 15) * 4;                // 0..60
#pragma unroll 1
    for (int qt = 0; qt < 4; ++qt) {
        // publish partials: accO[qt][nt][r] = O_part[q=qt*16+g*4+r][d=nt*16+fr]
#pragma unroll
        for (int nt = 0; nt < 4; ++nt)
#pragma unroll
            for (int r = 0; r < 4; ++r)
                Ored[w][g * 4 + r][nt * 16 + fr] = accO[qt][nt][r];
        __syncthreads();
        f32x4 s = {0.f, 0.f, 0.f, 0.f};
#pragma unroll
        for (int ww = 0; ww < 4; ++ww) {
            f32x4 t = *(const f32x4*)&Ored[ww][q_][d0];
            s[0] += t[0]; s[1] += t[1]; s[2] += t[2]; s[3] += t[3];
        }
        float ltot = Lred[0][qt][q_] + Lred[1][qt][q_]
                   + Lred[2][qt][q_] + Lred[3][qt][q_];
        float rls = 1.0f / ltot;
        long row = rowb + q0 + qt * 16 + q_;
        u16x4 ov;
#pragma unroll
        for (int j = 0; j < 4; ++j) ov[j] = f2b(s[j] * rls);
        *(u16x4*)(O + row * DD + h * 64 + d0) = ov;
        __syncthreads();
    }
}

// ---------------------------------------------------------------------------
// Weight prep. wprep512_kernel: nineteen 512x512 transposes via pointer table.
// ---------------------------------------------------------------------------
struct WP   { const float* s; u16* d; };
struct WTbl { WP e[19]; };

__global__ __launch_bounds__(256)
void wprep512_kernel(WTbl tbl) {
    const float* src = tbl.e[blockIdx.z].s;
    u16* dst = tbl.e[blockIdx.z].d;
    int k0 = blockIdx.y * 32, n0 = blockIdx.x * 32;
    __shared__ float tile[32][33];
    int tx = threadIdx.x & 31, ty = threadIdx.x >> 5;
#pragma unroll
    for (int i = 0; i < 4; ++i)
        tile[ty + 8 * i][tx] = src[(long)(k0 + ty + 8 * i) * 512 + n0 + tx];
    __syncthreads();
#pragma unroll
    for (int i = 0; i < 4; ++i) {
        int r = ty + 8 * i;
        dst[(long)(n0 + r) * 512 + k0 + tx] = f2b(tile[tx][r]);
    }
}

__global__ __launch_bounds__(256)
void wprep_kernel(const float* __restrict__ src, u16* __restrict__ dst,
                  int K, int N, long srcLS, long dstLS) {
    int l = blockIdx.z;
    src += (long)l * srcLS;
    dst += (long)l * dstLS;
    int k0 = blockIdx.y * 32, n0 = blockIdx.x * 32;
    __shared__ float tile[32][33];
    int tx = threadIdx.x & 31, ty = threadIdx.x >> 5;
#pragma unroll
    for (int i = 0; i < 4; ++i)
        tile[ty + 8 * i][tx] = src[(long)(k0 + ty + 8 * i) * N + n0 + tx];
    __syncthreads();
#pragma unroll
    for (int i = 0; i < 4; ++i) {
        int r = ty + 8 * i;
        dst[(long)(n0 + r) * K + k0 + tx] = f2b(tile[tx][r]);
    }
}

__global__ __launch_bounds__(256)
void bprep_kernel(const float* __restrict__ bq, const float* __restrict__ bk,
                  const float* __restrict__ bv, float* __restrict__ dst) {
    int i = blockIdx.x * 256 + threadIdx.x;
    int l = i / 1536, j = i - l * 1536;
    float v = (j < 512) ? bq[l * 512 + j]
            : (j < 1024) ? bk[l * 512 + j - 512]
                         : bv[l * 512 + j - 1024];
    dst[i] = v;
}

__global__ __launch_bounds__(256)
void f2b_kernel(const float* __restrict__ in, u16* __restrict__ out, int n) {
    int i = blockIdx.x * 256 + threadIdx.x;
    if (i < n) out[i] = f2b(in[i]);
}

__global__ __launch_bounds__(256)
void zero_kernel(float* __restrict__ p, int n) {
    int i = blockIdx.x * 256 + threadIdx.x;
    if (i < n) p[i] = 0.0f;
}

__global__ __launch_bounds__(256)
void colmean_kernel(const float* __restrict__ Hn, float* __restrict__ XM) {
    int blk = blockIdx.x;
    int b = blk >> 5;
    int r0 = (blk & 31) * 32;
    int tid = threadIdx.x;
    float acc0 = 0.0f, acc1 = 0.0f;
    for (int r = 0; r < 32; ++r) {
        long off = ((long)b * TT + r0 + r) * DD + tid;
        acc0 += Hn[off];
        acc1 += Hn[off + 256];
    }
    atomicAdd(&XM[b * DD + tid], acc0);
    atomicAdd(&XM[b * DD + tid + 256], acc1);
}

__global__ __launch_bounds__(256)
void cls_kernel(const float* __restrict__ XM, const float* __restrict__ W,
                const float* __restrict__ bias, float* __restrict__ out) {
    int b = blockIdx.x;
    int tid = threadIdx.x;
    __shared__ float xm[DD];
    xm[tid] = XM[b * DD + tid] * (1.0f / TT);
    xm[tid + 256] = XM[b * DD + tid + 256] * (1.0f / TT);
    __syncthreads();
    if (tid < NCC) {
        float s = bias[tid];
        for (int d = 0; d < DD; ++d) s += xm[d] * W[d * NCC + tid];
        out[b * NCC + tid] = s;
    }
}

// ---------------------------------------------------------------------------
extern "C" void kernel_launch(void* const* d_in, const int* in_sizes, int n_in,
                              void* d_out, int out_size, void* d_ws, size_t ws_size,
                              hipStream_t stream) {
    const int*   tokens  = (const int*)d_in[0];
    const float* emb     = (const float*)d_in[1];
    const float* Wq      = (const float*)d_in[2];
    const float* bq      = (const float*)d_in[3];
    const float* Wk      = (const float*)d_in[4];
    const float* bk      = (const float*)d_in[5];
    const float* Wv      = (const float*)d_in[6];
    const float* bv      = (const float*)d_in[7];
    const float* Wo      = (const float*)d_in[8];
    const float* bo      = (const float*)d_in[9];
    const float* ln1_g   = (const float*)d_in[10];
    const float* ln1_b   = (const float*)d_in[11];
    const float* ln2_g   = (const float*)d_in[12];
    const float* ln2_b   = (const float*)d_in[13];
    const float* W1      = (const float*)d_in[14];
    const float* b1      = (const float*)d_in[15];
    const float* W2      = (const float*)d_in[16];
    const float* b2      = (const float*)d_in[17];
    const float* heavy_w = (const float*)d_in[18];
    const float* heavy_b = (const float*)d_in[19];
    const float* heavy_a1= (const float*)d_in[20];
    const float* heavy_a2= (const float*)d_in[21];
    const float* norm_g  = (const float*)d_in[22];
    const float* norm_b  = (const float*)d_in[23];
    const float* cls_W   = (const float*)d_in[24];
    const float* cls_b   = (const float*)d_in[25];
    float* out = (float*)d_out;

    char* p = (char*)d_ws;
    float* X    = (float*)p;  p += MDl * 4;
    u16*   Hh   = (u16*)p;    p += MDl * 2;
    u16*   QKVb = (u16*)p;
    u16*   FFb  = QKVb;
    u16*   T1   = QKVb;
    u16*   T2   = QKVb + MDl;
    float* LNout= (float*)QKVb;
    p += (long)MM * 1536 * 2;
    u16*   Ob   = (u16*)p;    p += MDl * 2;
    u16*   Xbf  = (u16*)p;    p += MDl * 2;
    u16*   WqkvT= (u16*)p;    p += 4L * 1536 * 512 * 2;
    u16*   WoT  = (u16*)p;    p += 4L * 512 * 512 * 2;
    u16*   W1T  = (u16*)p;    p += 4L * 2048 * 512 * 2;
    u16*   W2T  = (u16*)p;    p += 4L * 512 * 2048 * 2;
    u16*   WhT  = (u16*)p;    p += 3L * 512 * 512 * 2;
    float* bqkv = (float*)p;  p += 4L * 1536 * 4;
    float* XM   = (float*)p;  p += (long)BS * DD * 4;

    dim3 blk(256);
    dim3 blk512(512);

    WTbl tbl;
    for (int l = 0; l < 4; ++l) {
        tbl.e[l * 4 + 0] = {Wq + (long)l * 262144, WqkvT + (long)l * 786432};
        tbl.e[l * 4 + 1] = {Wk + (long)l * 262144, WqkvT + (long)l * 786432 + 262144};
        tbl.e[l * 4 + 2] = {Wv + (long)l * 262144, WqkvT + (long)l * 786432 + 524288};
        tbl.e[l * 4 + 3] = {Wo + (long)l * 262144, WoT + (long)l * 262144};
    }
    tbl.e[16] = {heavy_w,  WhT};
    tbl.e[17] = {heavy_a1, WhT + 262144};
    tbl.e[18] = {heavy_a2, WhT + 524288};
    wprep512_kernel<<<dim3(16, 16, 19), blk, 0, stream>>>(tbl);
    wprep_kernel<<<dim3(64, 16, 4), blk, 0, stream>>>(W1, W1T,  512, 2048, 1048576, 1048576);
    wprep_kernel<<<dim3(16, 64, 4), blk, 0, stream>>>(W2, W2T, 2048,  512, 1048576, 1048576);
    bprep_kernel<<<24, blk, 0, stream>>>(bq, bk, bv, bqkv);

    embed_kernel<<<MM * DD / 256, blk, 0, stream>>>(tokens, emb, X);

    dim3 gQKV(12, 64), g512(4, 64), gFF1(16, 64);

    for (int l = 0; l < LL; ++l) {
        ln_kernel<1><<<MM, blk, 0, stream>>>(X, Hh, ln1_g + l * DD, ln1_b + l * DD);
        mfma_gemm<1, 1, 0, 0><<<gQKV, blk512, 0, stream>>>(
            Hh, WqkvT + (long)l * 786432, bqkv + l * 1536, nullptr, QKVb, 1536, 512);
        attn_kernel<<<dim3(1024), blk, 0, stream>>>(QKVb, Ob);
        mfma_gemm<0, 1, 0, 1><<<g512, blk512, 0, stream>>>(
            Ob, WoT + (long)l * 262144, bo + l * DD, X, X, 512, 512);
        ln_kernel<1><<<MM, blk, 0, stream>>>(X, Hh, ln2_g + l * DD, ln2_b + l * DD);
        mfma_gemm<1, 1, 1, 0><<<gFF1, blk512, 0, stream>>>(
            Hh, W1T + (long)l * 1048576, b1 + l * FFD, nullptr, FFb, 2048, 512);
        mfma_gemm<0, 1, 0, 1><<<g512, blk512, 0, stream>>>(
            FFb, W2T + (long)l * 1048576, b2 + l * DD, X, X, 512, 2048);
    }

    f2b_kernel<<<MM * DD / 256, blk, 0, stream>>>(X, Xbf, MM * DD);
    mfma_gemm<1, 0, 0, 0><<<g512, blk512, 0, stream>>>(Xbf, WhT,          nullptr, nullptr, T1, 512, 512);
    mfma_gemm<1, 0, 0, 0><<<g512, blk512, 0, stream>>>(T1,  WhT + 262144, nullptr, nullptr, T2, 512, 512);
    mfma_gemm<0, 1, 2, 0><<<g512, blk512, 0, stream>>>(T2,  WhT + 524288, heavy_b, nullptr, X,  512, 512);

    ln_kernel<0><<<MM, blk, 0, stream>>>(X, LNout, norm_g, norm_b);
    zero_kernel<<<(BS * DD + 255) / 256, blk, 0, stream>>>(XM, BS * DD);
    colmean_kernel<<<256, blk, 0, stream>>>(LNout, XM);
    cls_kernel<<<BS, blk, 0, stream>>>(XM, cls_W, cls_b, out);
}

// Round 4
// 868.307 us; speedup vs baseline: 1.1073x; 1.1073x over previous
//
#include <hip/hip_runtime.h>
#include <math.h>

#define BS   8
#define TT   1024
#define DD   512
#define HH   8
#define LL   4
#define FFD  2048
#define NCC  10
#define MM   (BS*TT)
#define MDl  ((long)MM*DD)

typedef unsigned short u16;
typedef short  short8 __attribute__((ext_vector_type(8)));
typedef float  f32x4  __attribute__((ext_vector_type(4)));
typedef u16    u16x8  __attribute__((ext_vector_type(8)));
typedef u16    u16x4  __attribute__((ext_vector_type(4)));

static __device__ __forceinline__ u16 f2b(float f) {
    union { float f; unsigned u; } x; x.f = f;
    unsigned r = x.u + 0x7FFFu + ((x.u >> 16) & 1u);   // RNE
    return (u16)(r >> 16);
}
// round-half-up: 2 insts, differs from RNE only on exact ties (negligible)
static __device__ __forceinline__ u16 f2b_fast(float f) {
    union { float f; unsigned u; } x; x.f = f;
    return (u16)((x.u + 0x8000u) >> 16);
}
static __device__ __forceinline__ float b2f(u16 u) {
    union { unsigned u; float f; } x; x.u = ((unsigned)u) << 16;
    return x.f;
}

// ---------------------------------------------------------------------------
// Embedding + sinusoidal positional encoding  (X fp32)
// ---------------------------------------------------------------------------
__global__ __launch_bounds__(256)
void embed_kernel(const int* __restrict__ tok, const float* __restrict__ emb,
                  float* __restrict__ X) {
    int i = blockIdx.x * 256 + threadIdx.x;
    int d = i & (DD - 1);
    int row = i >> 9;
    int t = row & (TT - 1);
    int j = d >> 1;
    float freq = __expf((float)(2 * j) * (-9.210340371976184f / 512.0f));
    float ang = (float)t * freq;
    float pe = (d & 1) ? cosf(ang) : sinf(ang);
    X[i] = emb[(long)tok[row] * DD + d] + pe;
}

// ---------------------------------------------------------------------------
// LayerNorm over D=512; OUTBF: 1 -> bf16 out, 0 -> fp32 out
// ---------------------------------------------------------------------------
template<int OUTBF>
__global__ __launch_bounds__(256)
void ln_kernel(const float* __restrict__ in, void* __restrict__ outp,
               const float* __restrict__ g, const float* __restrict__ b) {
    int row = blockIdx.x;
    int tid = threadIdx.x;
    const float* x = in + (long)row * DD;
    float x1 = x[tid], x2 = x[tid + 256];
    __shared__ float red[256], red2[256];
    red[tid] = x1 + x2;
    red2[tid] = x1 * x1 + x2 * x2;
    __syncthreads();
    for (int st = 128; st > 0; st >>= 1) {
        if (tid < st) { red[tid] += red[tid + st]; red2[tid] += red2[tid + st]; }
        __syncthreads();
    }
    float mean = red[0] * (1.0f / DD);
    float var = red2[0] * (1.0f / DD) - mean * mean;
    float rstd = rsqrtf(var + 1e-5f);
    float y1 = (x1 - mean) * rstd * g[tid] + b[tid];
    float y2 = (x2 - mean) * rstd * g[tid + 256] + b[tid + 256];
    if (OUTBF) {
        u16* o = (u16*)outp + (long)row * DD;
        o[tid] = f2b(y1); o[tid + 256] = f2b(y2);
    } else {
        float* o = (float*)outp + (long)row * DD;
        o[tid] = y1; o[tid + 256] = y2;
    }
}

// ---------------------------------------------------------------------------
// bf16 MFMA GEMM: C[M=8192, N] = epi(A[M,K] @ W), W given as WT[N][K] bf16.
// 128x128 tile, BK=64, 512 threads (8 waves). Register-prefetch pipeline.
// ---------------------------------------------------------------------------
template<int OUTBF, int HAS_BIAS, int ACT, int HAS_RES>
__global__ __launch_bounds__(512, 2)
void mfma_gemm(const u16* __restrict__ A, const u16* __restrict__ BT,
               const float* __restrict__ bias, const float* __restrict__ R,
               void* __restrict__ Cout, int N, int K) {
    __shared__ __align__(16) u16 lds[17408];   // As(8192)+Bs(8192) | Cs(128x136)
    u16* As = lds;
    u16* Bs = lds + 8192;
    const int tid = threadIdx.x;
    const int lane = tid & 63;
    const int w = tid >> 6;                    // 0..7
    const int wm = w >> 1;                     // 0..3: rows [wm*32, wm*32+32)
    const int wn = w & 1;                      // 0..1: cols [wn*64, wn*64+64)
    const long bm = (long)blockIdx.y * 128;
    const long bn = (long)blockIdx.x * 128;

    f32x4 acc[2][4];
#pragma unroll
    for (int i = 0; i < 2; ++i)
#pragma unroll
        for (int j = 0; j < 4; ++j) acc[i][j] = {0.f, 0.f, 0.f, 0.f};

    // staging: thread -> row tid>>2 (0..127), chunks (tid&3)*2 + {0,1}
    const int srow = tid >> 2;
    const int sc0 = (tid & 3) * 2;
    const u16* Ag = A + (bm + srow) * K + sc0 * 8;
    const u16* Bg = BT + (bn + srow) * K + sc0 * 8;
    int soff[2];
#pragma unroll
    for (int j = 0; j < 2; ++j)
        soff[j] = srow * 64 + ((sc0 + j) ^ (srow & 7)) * 8;

    const int fr = lane & 15;
    const int g = lane >> 4;
    const int am0 = wm * 32 + fr;
    const int bn0 = wn * 64 + fr;
    const int sw = fr & 7;

    u16x8 sa[2][2], sb[2][2];
#pragma unroll
    for (int j = 0; j < 2; ++j) {          // prologue: tile k0=0 -> regs
        sa[0][j] = *(const u16x8*)(Ag + j * 8);
        sb[0][j] = *(const u16x8*)(Bg + j * 8);
    }

    for (int k0 = 0; k0 < K; k0 += 128) {
#pragma unroll
        for (int half = 0; half < 2; ++half) {
            const int cb = half, nb = half ^ 1;
            __syncthreads();               // prior frag reads done
#pragma unroll
            for (int j = 0; j < 2; ++j) {
                *(u16x8*)&As[soff[j]] = sa[cb][j];
                *(u16x8*)&Bs[soff[j]] = sb[cb][j];
            }
            const int knext = k0 + (half + 1) * 64;
            if (knext < K) {               // prefetch next tile -> regs
#pragma unroll
                for (int j = 0; j < 2; ++j) {
                    sa[nb][j] = *(const u16x8*)(Ag + knext + j * 8);
                    sb[nb][j] = *(const u16x8*)(Bg + knext + j * 8);
                }
            }
            __syncthreads();               // staged tile visible
#pragma unroll
            for (int kk = 0; kk < 2; ++kk) {
                const int pos = ((kk << 2) + g) ^ sw;
                short8 af[2], bfv[4];
#pragma unroll
                for (int mi = 0; mi < 2; ++mi)
                    af[mi] = *(const short8*)&As[(am0 + mi * 16) * 64 + pos * 8];
#pragma unroll
                for (int ni = 0; ni < 4; ++ni)
                    bfv[ni] = *(const short8*)&Bs[(bn0 + ni * 16) * 64 + pos * 8];
#pragma unroll
                for (int mi = 0; mi < 2; ++mi)
#pragma unroll
                    for (int ni = 0; ni < 4; ++ni)
                        acc[mi][ni] = __builtin_amdgcn_mfma_f32_16x16x32_bf16(
                            af[mi], bfv[ni], acc[mi][ni], 0, 0, 0);
            }
        }
    }

    // C/D layout: col = lane&15, row = (lane>>4)*4 + reg
    const int erow0 = wm * 32 + g * 4;
    const int ecol0 = wn * 64 + fr;

    if (OUTBF) {
        __syncthreads();
#pragma unroll
        for (int ni = 0; ni < 4; ++ni) {
            const long col = bn + ecol0 + ni * 16;
            float bv = 0.f;
            if (HAS_BIAS) bv = bias[col];
#pragma unroll
            for (int mi = 0; mi < 2; ++mi)
#pragma unroll
                for (int r = 0; r < 4; ++r) {
                    const int row = erow0 + mi * 16 + r;
                    float v = acc[mi][ni][r];
                    if (HAS_BIAS) v += bv;
                    if (ACT == 1) v = 0.5f * v * (1.0f + erff(v * 0.70710678118654752f));
                    if (ACT == 2) v = tanhf(v);
                    if (HAS_RES) v += R[(bm + row) * N + col];
                    lds[row * 136 + ecol0 + ni * 16] = f2b(v);
                }
        }
        __syncthreads();
        const int srow2 = tid >> 4;                // 0..31
        const int sch2 = tid & 15;
        u16* Cp = (u16*)Cout;
#pragma unroll
        for (int rr = 0; rr < 4; ++rr) {
            const int row = srow2 + rr * 32;
            u16x8 vv = *(const u16x8*)&lds[row * 136 + sch2 * 8];
            *(u16x8*)(Cp + (bm + row) * N + bn + sch2 * 8) = vv;
        }
    } else {
#pragma unroll
        for (int ni = 0; ni < 4; ++ni) {
            const long col = bn + ecol0 + ni * 16;
            float bv = 0.f;
            if (HAS_BIAS) bv = bias[col];
#pragma unroll
            for (int mi = 0; mi < 2; ++mi)
#pragma unroll
                for (int r = 0; r < 4; ++r) {
                    const long row = bm + erow0 + mi * 16 + r;
                    float v = acc[mi][ni][r];
                    if (HAS_BIAS) v += bv;
                    if (ACT == 1) v = 0.5f * v * (1.0f + erff(v * 0.70710678118654752f));
                    if (ACT == 2) v = tanhf(v);
                    if (HAS_RES) v += R[row * N + col];
                    ((float*)Cout)[row * N + col] = v;
                }
        }
    }
}

// ---------------------------------------------------------------------------
// MFMA flash attention — R10: barrier-free swapped-QK, SCRATCH FIX.
// R9 post-mortem: WRITE_SIZE 8MB->133MB, VGPR 96 (too low for accO+qf live)
// => the epilogue's `#pragma unroll 1 for(qt)` runtime-indexed accO[qt],
// demoting the WHOLE accumulator array to scratch (guide rule #20); every
// main-loop MFMA then round-tripped local memory (67MB+ scratch traffic).
// Fix: fully unroll the epilogue qt loop -> all accO indices compile-time.
// Structure (proven correct in R9, absmax 9.8e-4):
//  * swapped QK^T: mfma(K,Q) -> lane holds P[q=lane&15][keys g*4+r] == the PV
//    A-frag layout (k-slot g*8+j -> key g*4+j for j<4, zeros j>=4; V B-frag
//    uses the same k-slot map so zeros cancel). P never touches LDS.
//  * waves own KEY slices; K-frags direct from global (L2-resident); only the
//    private 16-key V^T slice goes through LDS -> NO barriers in main loop.
//  * cross-wave O/lsum reduction once at block end.
// Block: 64 q, 4 waves, grid 1024 with XCD swizzle (FETCH 12MB proven in R7).
// ---------------------------------------------------------------------------
__global__ __launch_bounds__(256, 2)
void attn_kernel(const u16* __restrict__ QKV, u16* __restrict__ O) {
    const int id = blockIdx.x;                 // 0..1023
    const int bh = ((id >> 7) << 3) | (id & 7);// bhHi*8 + xcd, 0..63
    const int qblk = (id >> 3) & 15;           // 0..15
    const int h = bh & 7;
    const int b = bh >> 3;
    const int tid = threadIdx.x;
    const int lane = tid & 63;
    const int w = tid >> 6;                    // 0..3 : keys [w*16, w*16+16)
    const int fr = lane & 15;
    const int g = lane >> 4;

    __shared__ __align__(16) unsigned char smem[20480];
    u16* Vt = (u16*)smem;                      // [w][buf][64*20] u16
    float (*Ored)[16][68] = (float(*)[16][68])smem;  // [4][16][68] f32
    __shared__ float Lred[4][4][16];

    const long rowb = (long)b * TT;
    const int q0 = qblk * 64;

    // Q fragments (held all kernel): qf[qt][hf], q = q0+qt*16+fr, d = hf*32+g*8
    short8 qf[4][2];
#pragma unroll
    for (int qt = 0; qt < 4; ++qt)
#pragma unroll
        for (int hf = 0; hf < 2; ++hf)
            qf[qt][hf] = *(const short8*)(QKV + (rowb + q0 + qt * 16 + fr) * 1536
                                          + h * 64 + hf * 32 + g * 8);

    f32x4 accO[4][4];
    float lsum[4];
#pragma unroll
    for (int qt = 0; qt < 4; ++qt) {
        lsum[qt] = 0.f;
#pragma unroll
        for (int nt = 0; nt < 4; ++nt) accO[qt][nt] = {0.f, 0.f, 0.f, 0.f};
    }

    const int vkp = lane & 7;                  // key pair 2vkp, 2vkp+1
    const int vd0 = (lane >> 3) * 8;           // 8 d values
    u16* Vw0 = Vt + w * 2560;                  // wave's 2 buffers (u16 units)

    auto load_k = [&](int kt_, u16x8* kr_) {
        const u16* kp = QKV + (rowb + (long)kt_ * 64 + w * 16 + fr) * 1536
                        + 512 + h * 64 + g * 8;
        kr_[0] = *(const u16x8*)kp;
        kr_[1] = *(const u16x8*)(kp + 32);
    };
    auto load_v = [&](int kt_, u16x8* vr_) {
        const u16* vp = QKV + (rowb + (long)kt_ * 64 + w * 16 + vkp * 2) * 1536
                        + 1024 + h * 64 + vd0;
        vr_[0] = *(const u16x8*)vp;
        vr_[1] = *(const u16x8*)(vp + 1536);
    };
    auto stage_v = [&](int buf, u16x8* vr_) {
        unsigned* Vt32 = (unsigned*)(Vw0 + buf * 1280);
#pragma unroll
        for (int j = 0; j < 8; ++j)
            Vt32[(vd0 + j) * 10 + vkp] =
                (unsigned)vr_[0][j] | ((unsigned)vr_[1][j] << 16);
    };
    auto compute = [&](int buf, u16x8* kr_) {
        const u16* Vw = Vw0 + buf * 1280;
        // V B-frags (shared over qt): elem j<4 = V[key g*4+j][d=nt*16+fr], j>=4 = 0
        short8 vb[4];
#pragma unroll
        for (int nt = 0; nt < 4; ++nt) {
            union { short8 s; u16x4 h2[2]; } u;
            u.h2[0] = *(const u16x4*)(Vw + (nt * 16 + fr) * 20 + g * 4);
            u.h2[1] = (u16x4){0, 0, 0, 0};
            vb[nt] = u.s;
        }
#pragma unroll
        for (int qt = 0; qt < 4; ++qt) {
            f32x4 st = {0.f, 0.f, 0.f, 0.f};
            st = __builtin_amdgcn_mfma_f32_16x16x32_bf16(kr_[0], qf[qt][0], st, 0, 0, 0);
            st = __builtin_amdgcn_mfma_f32_16x16x32_bf16(kr_[1], qf[qt][1], st, 0, 0, 0);
            // P -> bf16 via proven f2b_fast; lsum sums the ROUNDED values so
            // softmax numerator/denominator are exactly consistent.
            u16 p0 = f2b_fast(exp2f(st[0] * 0.18033688011112042f));
            u16 p1 = f2b_fast(exp2f(st[1] * 0.18033688011112042f));
            u16 p2 = f2b_fast(exp2f(st[2] * 0.18033688011112042f));
            u16 p3 = f2b_fast(exp2f(st[3] * 0.18033688011112042f));
            lsum[qt] += (b2f(p0) + b2f(p1)) + (b2f(p2) + b2f(p3));
            union { short8 s; unsigned u[4]; } pu;
            pu.u[0] = (unsigned)p0 | ((unsigned)p1 << 16);
            pu.u[1] = (unsigned)p2 | ((unsigned)p3 << 16);
            pu.u[2] = 0; pu.u[3] = 0;
#pragma unroll
            for (int nt = 0; nt < 4; ++nt)
                accO[qt][nt] = __builtin_amdgcn_mfma_f32_16x16x32_bf16(
                    pu.s, vb[nt], accO[qt][nt], 0, 0, 0);
        }
    };

    u16x8 krA[2], vrA[2], krB[2], vrB[2];
    load_k(0, krA); load_v(0, vrA);
    load_k(1, krB); load_v(1, vrB);
    stage_v(0, vrA);

#pragma unroll 1
    for (int kt = 0; kt < 16; kt += 2) {
        stage_v(1, vrB);                          // tile kt+1 (loaded >=1 tile ago)
        compute(0, krA);                          // tile kt
        if (kt + 2 < 16) { load_k(kt + 2, krA); load_v(kt + 2, vrA); }
        compute(1, krB);                          // tile kt+1
        if (kt + 2 < 16) {
            stage_v(0, vrA);                      // tile kt+2 (arrived during compute)
            load_k(kt + 3, krB); load_v(kt + 3, vrB);
        }
    }

    // lsum: reduce over g-groups (keys g*4+r live per-g), publish per wave
#pragma unroll
    for (int qt = 0; qt < 4; ++qt) {
        float s = lsum[qt];
        s += __shfl_xor(s, 16, 64);
        s += __shfl_xor(s, 32, 64);
        Lred[w][qt][fr] = s;                      // 4 lanes same addr+value, benign
    }
    __syncthreads();                              // all waves done with Vt + Lred

    const int q_ = tid >> 4;                      // 0..15
    const int d0 = (tid & 15) * 4;                // 0..60
    // FULLY unrolled: accO[qt] must be compile-time indexed or the whole
    // array demotes to scratch (R9: 133MB writes). Barriers in a fully
    // unrolled uniform loop are fine.
#pragma unroll
    for (int qt = 0; qt < 4; ++qt) {
        // publish partials: accO[qt][nt][r] = O_part[q=qt*16+g*4+r][d=nt*16+fr]
#pragma unroll
        for (int nt = 0; nt < 4; ++nt)
#pragma unroll
            for (int r = 0; r < 4; ++r)
                Ored[w][g * 4 + r][nt * 16 + fr] = accO[qt][nt][r];
        __syncthreads();
        f32x4 s = {0.f, 0.f, 0.f, 0.f};
#pragma unroll
        for (int ww = 0; ww < 4; ++ww) {
            f32x4 t = *(const f32x4*)&Ored[ww][q_][d0];
            s[0] += t[0]; s[1] += t[1]; s[2] += t[2]; s[3] += t[3];
        }
        float ltot = Lred[0][qt][q_] + Lred[1][qt][q_]
                   + Lred[2][qt][q_] + Lred[3][qt][q_];
        float rls = 1.0f / ltot;
        long row = rowb + q0 + qt * 16 + q_;
        u16x4 ov;
#pragma unroll
        for (int j = 0; j < 4; ++j) ov[j] = f2b(s[j] * rls);
        *(u16x4*)(O + row * DD + h * 64 + d0) = ov;
        __syncthreads();
    }
}

// ---------------------------------------------------------------------------
// Weight prep. wprep512_kernel: nineteen 512x512 transposes via pointer table.
// ---------------------------------------------------------------------------
struct WP   { const float* s; u16* d; };
struct WTbl { WP e[19]; };

__global__ __launch_bounds__(256)
void wprep512_kernel(WTbl tbl) {
    const float* src = tbl.e[blockIdx.z].s;
    u16* dst = tbl.e[blockIdx.z].d;
    int k0 = blockIdx.y * 32, n0 = blockIdx.x * 32;
    __shared__ float tile[32][33];
    int tx = threadIdx.x & 31, ty = threadIdx.x >> 5;
#pragma unroll
    for (int i = 0; i < 4; ++i)
        tile[ty + 8 * i][tx] = src[(long)(k0 + ty + 8 * i) * 512 + n0 + tx];
    __syncthreads();
#pragma unroll
    for (int i = 0; i < 4; ++i) {
        int r = ty + 8 * i;
        dst[(long)(n0 + r) * 512 + k0 + tx] = f2b(tile[tx][r]);
    }
}

__global__ __launch_bounds__(256)
void wprep_kernel(const float* __restrict__ src, u16* __restrict__ dst,
                  int K, int N, long srcLS, long dstLS) {
    int l = blockIdx.z;
    src += (long)l * srcLS;
    dst += (long)l * dstLS;
    int k0 = blockIdx.y * 32, n0 = blockIdx.x * 32;
    __shared__ float tile[32][33];
    int tx = threadIdx.x & 31, ty = threadIdx.x >> 5;
#pragma unroll
    for (int i = 0; i < 4; ++i)
        tile[ty + 8 * i][tx] = src[(long)(k0 + ty + 8 * i) * N + n0 + tx];
    __syncthreads();
#pragma unroll
    for (int i = 0; i < 4; ++i) {
        int r = ty + 8 * i;
        dst[(long)(n0 + r) * K + k0 + tx] = f2b(tile[tx][r]);
    }
}

__global__ __launch_bounds__(256)
void bprep_kernel(const float* __restrict__ bq, const float* __restrict__ bk,
                  const float* __restrict__ bv, float* __restrict__ dst) {
    int i = blockIdx.x * 256 + threadIdx.x;
    int l = i / 1536, j = i - l * 1536;
    float v = (j < 512) ? bq[l * 512 + j]
            : (j < 1024) ? bk[l * 512 + j - 512]
                         : bv[l * 512 + j - 1024];
    dst[i] = v;
}

__global__ __launch_bounds__(256)
void f2b_kernel(const float* __restrict__ in, u16* __restrict__ out, int n) {
    int i = blockIdx.x * 256 + threadIdx.x;
    if (i < n) out[i] = f2b(in[i]);
}

__global__ __launch_bounds__(256)
void zero_kernel(float* __restrict__ p, int n) {
    int i = blockIdx.x * 256 + threadIdx.x;
    if (i < n) p[i] = 0.0f;
}

__global__ __launch_bounds__(256)
void colmean_kernel(const float* __restrict__ Hn, float* __restrict__ XM) {
    int blk = blockIdx.x;
    int b = blk >> 5;
    int r0 = (blk & 31) * 32;
    int tid = threadIdx.x;
    float acc0 = 0.0f, acc1 = 0.0f;
    for (int r = 0; r < 32; ++r) {
        long off = ((long)b * TT + r0 + r) * DD + tid;
        acc0 += Hn[off];
        acc1 += Hn[off + 256];
    }
    atomicAdd(&XM[b * DD + tid], acc0);
    atomicAdd(&XM[b * DD + tid + 256], acc1);
}

__global__ __launch_bounds__(256)
void cls_kernel(const float* __restrict__ XM, const float* __restrict__ W,
                const float* __restrict__ bias, float* __restrict__ out) {
    int b = blockIdx.x;
    int tid = threadIdx.x;
    __shared__ float xm[DD];
    xm[tid] = XM[b * DD + tid] * (1.0f / TT);
    xm[tid + 256] = XM[b * DD + tid + 256] * (1.0f / TT);
    __syncthreads();
    if (tid < NCC) {
        float s = bias[tid];
        for (int d = 0; d < DD; ++d) s += xm[d] * W[d * NCC + tid];
        out[b * NCC + tid] = s;
    }
}

// ---------------------------------------------------------------------------
extern "C" void kernel_launch(void* const* d_in, const int* in_sizes, int n_in,
                              void* d_out, int out_size, void* d_ws, size_t ws_size,
                              hipStream_t stream) {
    const int*   tokens  = (const int*)d_in[0];
    const float* emb     = (const float*)d_in[1];
    const float* Wq      = (const float*)d_in[2];
    const float* bq      = (const float*)d_in[3];
    const float* Wk      = (const float*)d_in[4];
    const float* bk      = (const float*)d_in[5];
    const float* Wv      = (const float*)d_in[6];
    const float* bv      = (const float*)d_in[7];
    const float* Wo      = (const float*)d_in[8];
    const float* bo      = (const float*)d_in[9];
    const float* ln1_g   = (const float*)d_in[10];
    const float* ln1_b   = (const float*)d_in[11];
    const float* ln2_g   = (const float*)d_in[12];
    const float* ln2_b   = (const float*)d_in[13];
    const float* W1      = (const float*)d_in[14];
    const float* b1      = (const float*)d_in[15];
    const float* W2      = (const float*)d_in[16];
    const float* b2      = (const float*)d_in[17];
    const float* heavy_w = (const float*)d_in[18];
    const float* heavy_b = (const float*)d_in[19];
    const float* heavy_a1= (const float*)d_in[20];
    const float* heavy_a2= (const float*)d_in[21];
    const float* norm_g  = (const float*)d_in[22];
    const float* norm_b  = (const float*)d_in[23];
    const float* cls_W   = (const float*)d_in[24];
    const float* cls_b   = (const float*)d_in[25];
    float* out = (float*)d_out;

    char* p = (char*)d_ws;
    float* X    = (float*)p;  p += MDl * 4;
    u16*   Hh   = (u16*)p;    p += MDl * 2;
    u16*   QKVb = (u16*)p;
    u16*   FFb  = QKVb;
    u16*   T1   = QKVb;
    u16*   T2   = QKVb + MDl;
    float* LNout= (float*)QKVb;
    p += (long)MM * 1536 * 2;
    u16*   Ob   = (u16*)p;    p += MDl * 2;
    u16*   Xbf  = (u16*)p;    p += MDl * 2;
    u16*   WqkvT= (u16*)p;    p += 4L * 1536 * 512 * 2;
    u16*   WoT  = (u16*)p;    p += 4L * 512 * 512 * 2;
    u16*   W1T  = (u16*)p;    p += 4L * 2048 * 512 * 2;
    u16*   W2T  = (u16*)p;    p += 4L * 512 * 2048 * 2;
    u16*   WhT  = (u16*)p;    p += 3L * 512 * 512 * 2;
    float* bqkv = (float*)p;  p += 4L * 1536 * 4;
    float* XM   = (float*)p;  p += (long)BS * DD * 4;

    dim3 blk(256);
    dim3 blk512(512);

    WTbl tbl;
    for (int l = 0; l < 4; ++l) {
        tbl.e[l * 4 + 0] = {Wq + (long)l * 262144, WqkvT + (long)l * 786432};
        tbl.e[l * 4 + 1] = {Wk + (long)l * 262144, WqkvT + (long)l * 786432 + 262144};
        tbl.e[l * 4 + 2] = {Wv + (long)l * 262144, WqkvT + (long)l * 786432 + 524288};
        tbl.e[l * 4 + 3] = {Wo + (long)l * 262144, WoT + (long)l * 262144};
    }
    tbl.e[16] = {heavy_w,  WhT};
    tbl.e[17] = {heavy_a1, WhT + 262144};
    tbl.e[18] = {heavy_a2, WhT + 524288};
    wprep512_kernel<<<dim3(16, 16, 19), blk, 0, stream>>>(tbl);
    wprep_kernel<<<dim3(64, 16, 4), blk, 0, stream>>>(W1, W1T,  512, 2048, 1048576, 1048576);
    wprep_kernel<<<dim3(16, 64, 4), blk, 0, stream>>>(W2, W2T, 2048,  512, 1048576, 1048576);
    bprep_kernel<<<24, blk, 0, stream>>>(bq, bk, bv, bqkv);

    embed_kernel<<<MM * DD / 256, blk, 0, stream>>>(tokens, emb, X);

    dim3 gQKV(12, 64), g512(4, 64), gFF1(16, 64);

    for (int l = 0; l < LL; ++l) {
        ln_kernel<1><<<MM, blk, 0, stream>>>(X, Hh, ln1_g + l * DD, ln1_b + l * DD);
        mfma_gemm<1, 1, 0, 0><<<gQKV, blk512, 0, stream>>>(
            Hh, WqkvT + (long)l * 786432, bqkv + l * 1536, nullptr, QKVb, 1536, 512);
        attn_kernel<<<dim3(1024), blk, 0, stream>>>(QKVb, Ob);
        mfma_gemm<0, 1, 0, 1><<<g512, blk512, 0, stream>>>(
            Ob, WoT + (long)l * 262144, bo + l * DD, X, X, 512, 512);
        ln_kernel<1><<<MM, blk, 0, stream>>>(X, Hh, ln2_g + l * DD, ln2_b + l * DD);
        mfma_gemm<1, 1, 1, 0><<<gFF1, blk512, 0, stream>>>(
            Hh, W1T + (long)l * 1048576, b1 + l * FFD, nullptr, FFb, 2048, 512);
        mfma_gemm<0, 1, 0, 1><<<g512, blk512, 0, stream>>>(
            FFb, W2T + (long)l * 1048576, b2 + l * DD, X, X, 512, 2048);
    }

    f2b_kernel<<<MM * DD / 256, blk, 0, stream>>>(X, Xbf, MM * DD);
    mfma_gemm<1, 0, 0, 0><<<g512, blk512, 0, stream>>>(Xbf, WhT,          nullptr, nullptr, T1, 512, 512);
    mfma_gemm<1, 0, 0, 0><<<g512, blk512, 0, stream>>>(T1,  WhT + 262144, nullptr, nullptr, T2, 512, 512);
    mfma_gemm<0, 1, 2, 0><<<g512, blk512, 0, stream>>>(T2,  WhT + 524288, heavy_b, nullptr, X,  512, 512);

    ln_kernel<0><<<MM, blk, 0, stream>>>(X, LNout, norm_g, norm_b);
    zero_kernel<<<(BS * DD + 255) / 256, blk, 0, stream>>>(XM, BS * DD);
    colmean_kernel<<<256, blk, 0, stream>>>(LNout, XM);
    cls_kernel<<<BS, blk, 0, stream>>>(XM, cls_W, cls_b, out);
}

// Round 6
// 860.625 us; speedup vs baseline: 1.1172x; 1.0089x over previous
//
#include <hip/hip_runtime.h>
#include <math.h>

#define BS   8
#define TT   1024
#define DD   512
#define HH   8
#define LL   4
#define FFD  2048
#define NCC  10
#define MM   (BS*TT)
#define MDl  ((long)MM*DD)

typedef unsigned short u16;
typedef short  short8 __attribute__((ext_vector_type(8)));
typedef float  f32x4  __attribute__((ext_vector_type(4)));
typedef u16    u16x8  __attribute__((ext_vector_type(8)));
typedef u16    u16x4  __attribute__((ext_vector_type(4)));

static __device__ __forceinline__ u16 f2b(float f) {
    union { float f; unsigned u; } x; x.f = f;
    unsigned r = x.u + 0x7FFFu + ((x.u >> 16) & 1u);   // RNE
    return (u16)(r >> 16);
}
// round-half-up: 2 insts, differs from RNE only on exact ties (negligible)
static __device__ __forceinline__ u16 f2b_fast(float f) {
    union { float f; unsigned u; } x; x.f = f;
    return (u16)((x.u + 0x8000u) >> 16);
}
static __device__ __forceinline__ float b2f(u16 u) {
    union { unsigned u; float f; } x; x.u = ((unsigned)u) << 16;
    return x.f;
}

// ---------------------------------------------------------------------------
// Embedding + sinusoidal positional encoding  (X fp32)
// ---------------------------------------------------------------------------
__global__ __launch_bounds__(256)
void embed_kernel(const int* __restrict__ tok, const float* __restrict__ emb,
                  float* __restrict__ X) {
    int i = blockIdx.x * 256 + threadIdx.x;
    int d = i & (DD - 1);
    int row = i >> 9;
    int t = row & (TT - 1);
    int j = d >> 1;
    float freq = __expf((float)(2 * j) * (-9.210340371976184f / 512.0f));
    float ang = (float)t * freq;
    float pe = (d & 1) ? cosf(ang) : sinf(ang);
    X[i] = emb[(long)tok[row] * DD + d] + pe;
}

// ---------------------------------------------------------------------------
// LayerNorm over D=512; OUTBF: 1 -> bf16 out, 0 -> fp32 out
// ---------------------------------------------------------------------------
template<int OUTBF>
__global__ __launch_bounds__(256)
void ln_kernel(const float* __restrict__ in, void* __restrict__ outp,
               const float* __restrict__ g, const float* __restrict__ b) {
    int row = blockIdx.x;
    int tid = threadIdx.x;
    const float* x = in + (long)row * DD;
    float x1 = x[tid], x2 = x[tid + 256];
    __shared__ float red[256], red2[256];
    red[tid] = x1 + x2;
    red2[tid] = x1 * x1 + x2 * x2;
    __syncthreads();
    for (int st = 128; st > 0; st >>= 1) {
        if (tid < st) { red[tid] += red[tid + st]; red2[tid] += red2[tid + st]; }
        __syncthreads();
    }
    float mean = red[0] * (1.0f / DD);
    float var = red2[0] * (1.0f / DD) - mean * mean;
    float rstd = rsqrtf(var + 1e-5f);
    float y1 = (x1 - mean) * rstd * g[tid] + b[tid];
    float y2 = (x2 - mean) * rstd * g[tid + 256] + b[tid + 256];
    if (OUTBF) {
        u16* o = (u16*)outp + (long)row * DD;
        o[tid] = f2b(y1); o[tid + 256] = f2b(y2);
    } else {
        float* o = (float*)outp + (long)row * DD;
        o[tid] = y1; o[tid + 256] = y2;
    }
}

// ---------------------------------------------------------------------------
// bf16 MFMA GEMM: C[M=8192, N] = epi(A[M,K] @ W), W given as WT[N][K] bf16.
// 128x128 tile, BK=64, 512 threads (8 waves). Register-prefetch pipeline.
// ---------------------------------------------------------------------------
template<int OUTBF, int HAS_BIAS, int ACT, int HAS_RES>
__global__ __launch_bounds__(512, 2)
void mfma_gemm(const u16* __restrict__ A, const u16* __restrict__ BT,
               const float* __restrict__ bias, const float* __restrict__ R,
               void* __restrict__ Cout, int N, int K) {
    __shared__ __align__(16) u16 lds[17408];   // As(8192)+Bs(8192) | Cs(128x136)
    u16* As = lds;
    u16* Bs = lds + 8192;
    const int tid = threadIdx.x;
    const int lane = tid & 63;
    const int w = tid >> 6;                    // 0..7
    const int wm = w >> 1;                     // 0..3: rows [wm*32, wm*32+32)
    const int wn = w & 1;                      // 0..1: cols [wn*64, wn*64+64)
    const long bm = (long)blockIdx.y * 128;
    const long bn = (long)blockIdx.x * 128;

    f32x4 acc[2][4];
#pragma unroll
    for (int i = 0; i < 2; ++i)
#pragma unroll
        for (int j = 0; j < 4; ++j) acc[i][j] = {0.f, 0.f, 0.f, 0.f};

    // staging: thread -> row tid>>2 (0..127), chunks (tid&3)*2 + {0,1}
    const int srow = tid >> 2;
    const int sc0 = (tid & 3) * 2;
    const u16* Ag = A + (bm + srow) * K + sc0 * 8;
    const u16* Bg = BT + (bn + srow) * K + sc0 * 8;
    int soff[2];
#pragma unroll
    for (int j = 0; j < 2; ++j)
        soff[j] = srow * 64 + ((sc0 + j) ^ (srow & 7)) * 8;

    const int fr = lane & 15;
    const int g = lane >> 4;
    const int am0 = wm * 32 + fr;
    const int bn0 = wn * 64 + fr;
    const int sw = fr & 7;

    u16x8 sa[2][2], sb[2][2];
#pragma unroll
    for (int j = 0; j < 2; ++j) {          // prologue: tile k0=0 -> regs
        sa[0][j] = *(const u16x8*)(Ag + j * 8);
        sb[0][j] = *(const u16x8*)(Bg + j * 8);
    }

    for (int k0 = 0; k0 < K; k0 += 128) {
#pragma unroll
        for (int half = 0; half < 2; ++half) {
            const int cb = half, nb = half ^ 1;
            __syncthreads();               // prior frag reads done
#pragma unroll
            for (int j = 0; j < 2; ++j) {
                *(u16x8*)&As[soff[j]] = sa[cb][j];
                *(u16x8*)&Bs[soff[j]] = sb[cb][j];
            }
            const int knext = k0 + (half + 1) * 64;
            if (knext < K) {               // prefetch next tile -> regs
#pragma unroll
                for (int j = 0; j < 2; ++j) {
                    sa[nb][j] = *(const u16x8*)(Ag + knext + j * 8);
                    sb[nb][j] = *(const u16x8*)(Bg + knext + j * 8);
                }
            }
            __syncthreads();               // staged tile visible
#pragma unroll
            for (int kk = 0; kk < 2; ++kk) {
                const int pos = ((kk << 2) + g) ^ sw;
                short8 af[2], bfv[4];
#pragma unroll
                for (int mi = 0; mi < 2; ++mi)
                    af[mi] = *(const short8*)&As[(am0 + mi * 16) * 64 + pos * 8];
#pragma unroll
                for (int ni = 0; ni < 4; ++ni)
                    bfv[ni] = *(const short8*)&Bs[(bn0 + ni * 16) * 64 + pos * 8];
#pragma unroll
                for (int mi = 0; mi < 2; ++mi)
#pragma unroll
                    for (int ni = 0; ni < 4; ++ni)
                        acc[mi][ni] = __builtin_amdgcn_mfma_f32_16x16x32_bf16(
                            af[mi], bfv[ni], acc[mi][ni], 0, 0, 0);
            }
        }
    }

    // C/D layout: col = lane&15, row = (lane>>4)*4 + reg
    const int erow0 = wm * 32 + g * 4;
    const int ecol0 = wn * 64 + fr;

    if (OUTBF) {
        __syncthreads();
#pragma unroll
        for (int ni = 0; ni < 4; ++ni) {
            const long col = bn + ecol0 + ni * 16;
            float bv = 0.f;
            if (HAS_BIAS) bv = bias[col];
#pragma unroll
            for (int mi = 0; mi < 2; ++mi)
#pragma unroll
                for (int r = 0; r < 4; ++r) {
                    const int row = erow0 + mi * 16 + r;
                    float v = acc[mi][ni][r];
                    if (HAS_BIAS) v += bv;
                    if (ACT == 1) v = 0.5f * v * (1.0f + erff(v * 0.70710678118654752f));
                    if (ACT == 2) v = tanhf(v);
                    if (HAS_RES) v += R[(bm + row) * N + col];
                    lds[row * 136 + ecol0 + ni * 16] = f2b(v);
                }
        }
        __syncthreads();
        const int srow2 = tid >> 4;                // 0..31
        const int sch2 = tid & 15;
        u16* Cp = (u16*)Cout;
#pragma unroll
        for (int rr = 0; rr < 4; ++rr) {
            const int row = srow2 + rr * 32;
            u16x8 vv = *(const u16x8*)&lds[row * 136 + sch2 * 8];
            *(u16x8*)(Cp + (bm + row) * N + bn + sch2 * 8) = vv;
        }
    } else {
#pragma unroll
        for (int ni = 0; ni < 4; ++ni) {
            const long col = bn + ecol0 + ni * 16;
            float bv = 0.f;
            if (HAS_BIAS) bv = bias[col];
#pragma unroll
            for (int mi = 0; mi < 2; ++mi)
#pragma unroll
                for (int r = 0; r < 4; ++r) {
                    const long row = bm + erow0 + mi * 16 + r;
                    float v = acc[mi][ni][r];
                    if (HAS_BIAS) v += bv;
                    if (ACT == 1) v = 0.5f * v * (1.0f + erff(v * 0.70710678118654752f));
                    if (ACT == 2) v = tanhf(v);
                    if (HAS_RES) v += R[row * N + col];
                    ((float*)Cout)[row * N + col] = v;
                }
        }
    }
}

// ---------------------------------------------------------------------------
// MFMA flash attention — R12: fused 32-key computes (R11 structure, vb
// ADDRESS FIX). R11 produced NaN: the vb reads added a spurious +nt*256 on
// top of the (nt*16+fr)*16 row term (nt counted twice), so vb1 read nt=2's
// rows and vb2/vb3 read PAST the wave's 1024-u32 buffer (neighbor wave /
// off-array garbage -> bf16 NaN encodings -> accO poisoned). Correct offset:
// (nt*16+fr)*16 + g*4. Everything else unchanged from R11:
//  * PV A-frag slots 0-3 = tile-a keys g*4+r, slots 4-7 = tile-b keys ->
//    all 8 slots real. PV MFMAs halve (32 vs 48 per wave per 32 keys).
//  * V staged per-wave as [d=64][32key] u32 rows; col encodes the slot map;
//    vb = one ds_read_b128 per nt, SHARED across qt.
//  * iterations halve -> register-prefetch distance ~2x (covers L3 latency).
//  * lsum = unrounded f32 sum of pv (R7-proven).
// Kept from R10 (proven): swapped QK^T P-layout, key-slice wave ownership,
// K-frags direct from global, no main-loop barriers, XCD swizzle (FETCH 12MB),
// fully-unrolled epilogue (rule #20).
// ---------------------------------------------------------------------------
__global__ __launch_bounds__(256, 2)
void attn_kernel(const u16* __restrict__ QKV, u16* __restrict__ O) {
    const int id = blockIdx.x;                 // 0..1023
    const int bh = ((id >> 7) << 3) | (id & 7);// bhHi*8 + xcd, 0..63
    const int qblk = (id >> 3) & 15;           // 0..15
    const int h = bh & 7;
    const int b = bh >> 3;
    const int tid = threadIdx.x;
    const int lane = tid & 63;
    const int w = tid >> 6;                    // 0..3 : keys [w*16, w*16+16) of each tile
    const int fr = lane & 15;
    const int g = lane >> 4;

    __shared__ __align__(16) unsigned Vt32[8192];        // [w][buf][64 d][16 u32] = 32KB
    float (*Ored)[16][68] = (float(*)[16][68])Vt32;      // 17.4KB overlay (epilogue)
    __shared__ float Lred[4][4][16];

    const long rowb = (long)b * TT;
    const int q0 = qblk * 64;

    // Q fragments (held all kernel): qf[qt][hf], q = q0+qt*16+fr, d = hf*32+g*8
    short8 qf[4][2];
#pragma unroll
    for (int qt = 0; qt < 4; ++qt)
#pragma unroll
        for (int hf = 0; hf < 2; ++hf)
            qf[qt][hf] = *(const short8*)(QKV + (rowb + q0 + qt * 16 + fr) * 1536
                                          + h * 64 + hf * 32 + g * 8);

    f32x4 accO[4][4];
    float lsum[4];
#pragma unroll
    for (int qt = 0; qt < 4; ++qt) {
        lsum[qt] = 0.f;
#pragma unroll
        for (int nt = 0; nt < 4; ++nt) accO[qt][nt] = {0.f, 0.f, 0.f, 0.f};
    }

    // V staging thread mapping: lane -> (group G, local key pair, d segment)
    const int G = lane & 1;                    // 0 = tile kt, 1 = tile kt+1
    const int kpair = (lane >> 1) & 7;         // local keys 2kpair, 2kpair+1
    const int dseg = lane >> 4;                // d in [dseg*16, dseg*16+16)
    // u16 col c = g*8 + j must hold key (j<4 ? a : b) + g*4 + (j&3):
    // u32 col = (kpair>>1)*4 + 2*G + (kpair&1)
    const int vcol = (kpair >> 1) * 4 + 2 * G + (kpair & 1);
    unsigned* Vw = Vt32 + w * 2048;            // wave region: 2 bufs x 1024 u32

    auto load_k = [&](int kt_, u16x8* kr_) {   // kr_[0..1]=tile kt_ halves, [2..3]=kt_+1
        const u16* kp0 = QKV + (rowb + (long)kt_ * 64 + w * 16 + fr) * 1536
                         + 512 + h * 64 + g * 8;
        kr_[0] = *(const u16x8*)kp0;
        kr_[1] = *(const u16x8*)(kp0 + 32);
        const u16* kp1 = kp0 + (long)64 * 1536;
        kr_[2] = *(const u16x8*)kp1;
        kr_[3] = *(const u16x8*)(kp1 + 32);
    };
    auto load_v = [&](int kt_, u16x8* vr_) {   // 2 keys x 16 d per lane
        const long krow = rowb + (long)(kt_ + G) * 64 + w * 16 + kpair * 2;
        const u16* vp = QKV + krow * 1536 + 1024 + h * 64 + dseg * 16;
        vr_[0] = *(const u16x8*)vp;            // key0, d 0..7
        vr_[1] = *(const u16x8*)(vp + 8);      // key0, d 8..15
        vr_[2] = *(const u16x8*)(vp + 1536);   // key1, d 0..7
        vr_[3] = *(const u16x8*)(vp + 1536 + 8);
    };
    auto stage_v = [&](int buf, u16x8* vr_) {
        unsigned* p = Vw + buf * 1024 + dseg * 16 * 16 + vcol;
#pragma unroll
        for (int jj = 0; jj < 8; ++jj)
            p[jj * 16] = (unsigned)vr_[0][jj] | ((unsigned)vr_[2][jj] << 16);
#pragma unroll
        for (int jj = 0; jj < 8; ++jj)
            p[(8 + jj) * 16] = (unsigned)vr_[1][jj] | ((unsigned)vr_[3][jj] << 16);
    };
    auto compute32 = [&](int buf, u16x8* kr_) {
        const unsigned* Vb = Vw + buf * 1024;
        // vb[nt]: lane (fr,g) holds V[key(g,j)][d=nt*16+fr] at u32 offset
        // (nt*16+fr)*16 + g*4 (row term already includes nt). One b128 each,
        // shared across all 4 qt.
        short8 vb0 = *(const short8*)(Vb + (0 * 16 + fr) * 16 + g * 4);
        short8 vb1 = *(const short8*)(Vb + (1 * 16 + fr) * 16 + g * 4);
        short8 vb2 = *(const short8*)(Vb + (2 * 16 + fr) * 16 + g * 4);
        short8 vb3 = *(const short8*)(Vb + (3 * 16 + fr) * 16 + g * 4);
#pragma unroll
        for (int qt = 0; qt < 4; ++qt) {
            f32x4 sa = {0.f, 0.f, 0.f, 0.f}, sb2 = {0.f, 0.f, 0.f, 0.f};
            sa  = __builtin_amdgcn_mfma_f32_16x16x32_bf16(kr_[0], qf[qt][0], sa, 0, 0, 0);
            sa  = __builtin_amdgcn_mfma_f32_16x16x32_bf16(kr_[1], qf[qt][1], sa, 0, 0, 0);
            sb2 = __builtin_amdgcn_mfma_f32_16x16x32_bf16(kr_[2], qf[qt][0], sb2, 0, 0, 0);
            sb2 = __builtin_amdgcn_mfma_f32_16x16x32_bf16(kr_[3], qf[qt][1], sb2, 0, 0, 0);
            const float SC = 0.18033688011112042f;       // log2(e)/8
            float pa0 = exp2f(sa[0] * SC),  pa1 = exp2f(sa[1] * SC);
            float pa2 = exp2f(sa[2] * SC),  pa3 = exp2f(sa[3] * SC);
            float pb0 = exp2f(sb2[0] * SC), pb1 = exp2f(sb2[1] * SC);
            float pb2 = exp2f(sb2[2] * SC), pb3 = exp2f(sb2[3] * SC);
            lsum[qt] += ((pa0 + pa1) + (pa2 + pa3)) + ((pb0 + pb1) + (pb2 + pb3));
            union { short8 s; unsigned u[4]; } pu;
            pu.u[0] = (unsigned)f2b_fast(pa0) | ((unsigned)f2b_fast(pa1) << 16);
            pu.u[1] = (unsigned)f2b_fast(pa2) | ((unsigned)f2b_fast(pa3) << 16);
            pu.u[2] = (unsigned)f2b_fast(pb0) | ((unsigned)f2b_fast(pb1) << 16);
            pu.u[3] = (unsigned)f2b_fast(pb2) | ((unsigned)f2b_fast(pb3) << 16);
            accO[qt][0] = __builtin_amdgcn_mfma_f32_16x16x32_bf16(pu.s, vb0, accO[qt][0], 0, 0, 0);
            accO[qt][1] = __builtin_amdgcn_mfma_f32_16x16x32_bf16(pu.s, vb1, accO[qt][1], 0, 0, 0);
            accO[qt][2] = __builtin_amdgcn_mfma_f32_16x16x32_bf16(pu.s, vb2, accO[qt][2], 0, 0, 0);
            accO[qt][3] = __builtin_amdgcn_mfma_f32_16x16x32_bf16(pu.s, vb3, accO[qt][3], 0, 0, 0);
        }
    };

    u16x8 krA[4], krB[4], vr[4];
    load_k(0, krA);  load_v(0, vr);
    stage_v(0, vr);                            // pair 0 -> buf0
    load_k(2, krB);  load_v(2, vr);            // pair 1 (tiles 2,3)

#pragma unroll 1
    for (int kt = 0; kt < 16; kt += 4) {       // 4 trips x 2 pair-computes
        stage_v(1, vr);                        // pair kt/2+1 -> buf1 (vr free after)
        compute32(0, krA);                     // pair kt/2 (tiles kt, kt+1)
        if (kt + 4 < 16) {
            load_k(kt + 4, krA); load_v(kt + 4, vr);
            stage_v(0, vr);                    // pair kt/2+2 -> buf0
            load_k(kt + 6, krB); load_v(kt + 6, vr);
        }
        compute32(1, krB);                     // pair kt/2+1 (tiles kt+2, kt+3)
    }

    // lsum: reduce over g-groups (keys g*4+r live per-g), publish per wave
#pragma unroll
    for (int qt = 0; qt < 4; ++qt) {
        float s = lsum[qt];
        s += __shfl_xor(s, 16, 64);
        s += __shfl_xor(s, 32, 64);
        Lred[w][qt][fr] = s;                   // 4 lanes same addr+value, benign
    }
    __syncthreads();                           // all waves done with Vt + Lred

    const int q_ = tid >> 4;                   // 0..15
    const int d0 = (tid & 15) * 4;             // 0..60
    // FULLY unrolled (rule #20: runtime accO index demotes array to scratch).
#pragma unroll
    for (int qt = 0; qt < 4; ++qt) {
        // publish partials: accO[qt][nt][r] = O_part[q=qt*16+g*4+r][d=nt*16+fr]
#pragma unroll
        for (int nt = 0; nt < 4; ++nt)
#pragma unroll
            for (int r = 0; r < 4; ++r)
                Ored[w][g * 4 + r][nt * 16 + fr] = accO[qt][nt][r];
        __syncthreads();
        f32x4 s = {0.f, 0.f, 0.f, 0.f};
#pragma unroll
        for (int ww = 0; ww < 4; ++ww) {
            f32x4 t = *(const f32x4*)&Ored[ww][q_][d0];
            s[0] += t[0]; s[1] += t[1]; s[2] += t[2]; s[3] += t[3];
        }
        float ltot = Lred[0][qt][q_] + Lred[1][qt][q_]
                   + Lred[2][qt][q_] + Lred[3][qt][q_];
        float rls = 1.0f / ltot;
        long row = rowb + q0 + qt * 16 + q_;
        u16x4 ov;
#pragma unroll
        for (int j = 0; j < 4; ++j) ov[j] = f2b(s[j] * rls);
        *(u16x4*)(O + row * DD + h * 64 + d0) = ov;
        __syncthreads();
    }
}

// ---------------------------------------------------------------------------
// Weight prep. wprep512_kernel: nineteen 512x512 transposes via pointer table.
// ---------------------------------------------------------------------------
struct WP   { const float* s; u16* d; };
struct WTbl { WP e[19]; };

__global__ __launch_bounds__(256)
void wprep512_kernel(WTbl tbl) {
    const float* src = tbl.e[blockIdx.z].s;
    u16* dst = tbl.e[blockIdx.z].d;
    int k0 = blockIdx.y * 32, n0 = blockIdx.x * 32;
    __shared__ float tile[32][33];
    int tx = threadIdx.x & 31, ty = threadIdx.x >> 5;
#pragma unroll
    for (int i = 0; i < 4; ++i)
        tile[ty + 8 * i][tx] = src[(long)(k0 + ty + 8 * i) * 512 + n0 + tx];
    __syncthreads();
#pragma unroll
    for (int i = 0; i < 4; ++i) {
        int r = ty + 8 * i;
        dst[(long)(n0 + r) * 512 + k0 + tx] = f2b(tile[tx][r]);
    }
}

__global__ __launch_bounds__(256)
void wprep_kernel(const float* __restrict__ src, u16* __restrict__ dst,
                  int K, int N, long srcLS, long dstLS) {
    int l = blockIdx.z;
    src += (long)l * srcLS;
    dst += (long)l * dstLS;
    int k0 = blockIdx.y * 32, n0 = blockIdx.x * 32;
    __shared__ float tile[32][33];
    int tx = threadIdx.x & 31, ty = threadIdx.x >> 5;
#pragma unroll
    for (int i = 0; i < 4; ++i)
        tile[ty + 8 * i][tx] = src[(long)(k0 + ty + 8 * i) * N + n0 + tx];
    __syncthreads();
#pragma unroll
    for (int i = 0; i < 4; ++i) {
        int r = ty + 8 * i;
        dst[(long)(n0 + r) * K + k0 + tx] = f2b(tile[tx][r]);
    }
}

__global__ __launch_bounds__(256)
void bprep_kernel(const float* __restrict__ bq, const float* __restrict__ bk,
                  const float* __restrict__ bv, float* __restrict__ dst) {
    int i = blockIdx.x * 256 + threadIdx.x;
    int l = i / 1536, j = i - l * 1536;
    float v = (j < 512) ? bq[l * 512 + j]
            : (j < 1024) ? bk[l * 512 + j - 512]
                         : bv[l * 512 + j - 1024];
    dst[i] = v;
}

__global__ __launch_bounds__(256)
void f2b_kernel(const float* __restrict__ in, u16* __restrict__ out, int n) {
    int i = blockIdx.x * 256 + threadIdx.x;
    if (i < n) out[i] = f2b(in[i]);
}

__global__ __launch_bounds__(256)
void zero_kernel(float* __restrict__ p, int n) {
    int i = blockIdx.x * 256 + threadIdx.x;
    if (i < n) p[i] = 0.0f;
}

__global__ __launch_bounds__(256)
void colmean_kernel(const float* __restrict__ Hn, float* __restrict__ XM) {
    int blk = blockIdx.x;
    int b = blk >> 5;
    int r0 = (blk & 31) * 32;
    int tid = threadIdx.x;
    float acc0 = 0.0f, acc1 = 0.0f;
    for (int r = 0; r < 32; ++r) {
        long off = ((long)b * TT + r0 + r) * DD + tid;
        acc0 += Hn[off];
        acc1 += Hn[off + 256];
    }
    atomicAdd(&XM[b * DD + tid], acc0);
    atomicAdd(&XM[b * DD + tid + 256], acc1);
}

__global__ __launch_bounds__(256)
void cls_kernel(const float* __restrict__ XM, const float* __restrict__ W,
                const float* __restrict__ bias, float* __restrict__ out) {
    int b = blockIdx.x;
    int tid = threadIdx.x;
    __shared__ float xm[DD];
    xm[tid] = XM[b * DD + tid] * (1.0f / TT);
    xm[tid + 256] = XM[b * DD + tid + 256] * (1.0f / TT);
    __syncthreads();
    if (tid < NCC) {
        float s = bias[tid];
        for (int d = 0; d < DD; ++d) s += xm[d] * W[d * NCC + tid];
        out[b * NCC + tid] = s;
    }
}

// ---------------------------------------------------------------------------
extern "C" void kernel_launch(void* const* d_in, const int* in_sizes, int n_in,
                              void* d_out, int out_size, void* d_ws, size_t ws_size,
                              hipStream_t stream) {
    const int*   tokens  = (const int*)d_in[0];
    const float* emb     = (const float*)d_in[1];
    const float* Wq      = (const float*)d_in[2];
    const float* bq      = (const float*)d_in[3];
    const float* Wk      = (const float*)d_in[4];
    const float* bk      = (const float*)d_in[5];
    const float* Wv      = (const float*)d_in[6];
    const float* bv      = (const float*)d_in[7];
    const float* Wo      = (const float*)d_in[8];
    const float* bo      = (const float*)d_in[9];
    const float* ln1_g   = (const float*)d_in[10];
    const float* ln1_b   = (const float*)d_in[11];
    const float* ln2_g   = (const float*)d_in[12];
    const float* ln2_b   = (const float*)d_in[13];
    const float* W1      = (const float*)d_in[14];
    const float* b1      = (const float*)d_in[15];
    const float* W2      = (const float*)d_in[16];
    const float* b2      = (const float*)d_in[17];
    const float* heavy_w = (const float*)d_in[18];
    const float* heavy_b = (const float*)d_in[19];
    const float* heavy_a1= (const float*)d_in[20];
    const float* heavy_a2= (const float*)d_in[21];
    const float* norm_g  = (const float*)d_in[22];
    const float* norm_b  = (const float*)d_in[23];
    const float* cls_W   = (const float*)d_in[24];
    const float* cls_b   = (const float*)d_in[25];
    float* out = (float*)d_out;

    char* p = (char*)d_ws;
    float* X    = (float*)p;  p += MDl * 4;
    u16*   Hh   = (u16*)p;    p += MDl * 2;
    u16*   QKVb = (u16*)p;
    u16*   FFb  = QKVb;
    u16*   T1   = QKVb;
    u16*   T2   = QKVb + MDl;
    float* LNout= (float*)QKVb;
    p += (long)MM * 1536 * 2;
    u16*   Ob   = (u16*)p;    p += MDl * 2;
    u16*   Xbf  = (u16*)p;    p += MDl * 2;
    u16*   WqkvT= (u16*)p;    p += 4L * 1536 * 512 * 2;
    u16*   WoT  = (u16*)p;    p += 4L * 512 * 512 * 2;
    u16*   W1T  = (u16*)p;    p += 4L * 2048 * 512 * 2;
    u16*   W2T  = (u16*)p;    p += 4L * 512 * 2048 * 2;
    u16*   WhT  = (u16*)p;    p += 3L * 512 * 512 * 2;
    float* bqkv = (float*)p;  p += 4L * 1536 * 4;
    float* XM   = (float*)p;  p += (long)BS * DD * 4;

    dim3 blk(256);
    dim3 blk512(512);

    WTbl tbl;
    for (int l = 0; l < 4; ++l) {
        tbl.e[l * 4 + 0] = {Wq + (long)l * 262144, WqkvT + (long)l * 786432};
        tbl.e[l * 4 + 1] = {Wk + (long)l * 262144, WqkvT + (long)l * 786432 + 262144};
        tbl.e[l * 4 + 2] = {Wv + (long)l * 262144, WqkvT + (long)l * 786432 + 524288};
        tbl.e[l * 4 + 3] = {Wo + (long)l * 262144, WoT + (long)l * 262144};
    }
    tbl.e[16] = {heavy_w,  WhT};
    tbl.e[17] = {heavy_a1, WhT + 262144};
    tbl.e[18] = {heavy_a2, WhT + 524288};
    wprep512_kernel<<<dim3(16, 16, 19), blk, 0, stream>>>(tbl);
    wprep_kernel<<<dim3(64, 16, 4), blk, 0, stream>>>(W1, W1T,  512, 2048, 1048576, 1048576);
    wprep_kernel<<<dim3(16, 64, 4), blk, 0, stream>>>(W2, W2T, 2048,  512, 1048576, 1048576);
    bprep_kernel<<<24, blk, 0, stream>>>(bq, bk, bv, bqkv);

    embed_kernel<<<MM * DD / 256, blk, 0, stream>>>(tokens, emb, X);

    dim3 gQKV(12, 64), g512(4, 64), gFF1(16, 64);

    for (int l = 0; l < LL; ++l) {
        ln_kernel<1><<<MM, blk, 0, stream>>>(X, Hh, ln1_g + l * DD, ln1_b + l * DD);
        mfma_gemm<1, 1, 0, 0><<<gQKV, blk512, 0, stream>>>(
            Hh, WqkvT + (long)l * 786432, bqkv + l * 1536, nullptr, QKVb, 1536, 512);
        attn_kernel<<<dim3(1024), blk, 0, stream>>>(QKVb, Ob);
        mfma_gemm<0, 1, 0, 1><<<g512, blk512, 0, stream>>>(
            Ob, WoT + (long)l * 262144, bo + l * DD, X, X, 512, 512);
        ln_kernel<1><<<MM, blk, 0, stream>>>(X, Hh, ln2_g + l * DD, ln2_b + l * DD);
        mfma_gemm<1, 1, 1, 0><<<gFF1, blk512, 0, stream>>>(
            Hh, W1T + (long)l * 1048576, b1 + l * FFD, nullptr, FFb, 2048, 512);
        mfma_gemm<0, 1, 0, 1><<<g512, blk512, 0, stream>>>(
            FFb, W2T + (long)l * 1048576, b2 + l * DD, X, X, 512, 2048);
    }

    f2b_kernel<<<MM * DD / 256, blk, 0, stream>>>(X, Xbf, MM * DD);
    mfma_gemm<1, 0, 0, 0><<<g512, blk512, 0, stream>>>(Xbf, WhT,          nullptr, nullptr, T1, 512, 512);
    mfma_gemm<1, 0, 0, 0><<<g512, blk512, 0, stream>>>(T1,  WhT + 262144, nullptr, nullptr, T2, 512, 512);
    mfma_gemm<0, 1, 2, 0><<<g512, blk512, 0, stream>>>(T2,  WhT + 524288, heavy_b, nullptr, X,  512, 512);

    ln_kernel<0><<<MM, blk, 0, stream>>>(X, LNout, norm_g, norm_b);
    zero_kernel<<<(BS * DD + 255) / 256, blk, 0, stream>>>(XM, BS * DD);
    colmean_kernel<<<256, blk, 0, stream>>>(LNout, XM);
    cls_kernel<<<BS, blk, 0, stream>>>(XM, cls_W, cls_b, out);
}